// Round 4
// baseline (28581.973 us; speedup 1.0000x reference)
//
#include <hip/hip_runtime.h>
#include <math.h>

#define TT 512
#define BB 32
#define DD 1280

// ---------------------------------------------------------------------------
// Kernel 1: x-projection GEMM.  XP[m][n] = bias[n] + sum_k X[m][k]*Wx[n][k]
// M = T*B = 16384, N = K = D = 1280.  fp32 (no fp32 MFMA on CDNA4).
// Unchanged (~550-700 us); revisit once the scan is < ~1.5x of it.
// ---------------------------------------------------------------------------
__launch_bounds__(256) __global__
void xproj_gemm(const float* __restrict__ X, const float* __restrict__ Wx,
                const float* __restrict__ bias, float* __restrict__ XP)
{
    __shared__ __align__(16) float As[16][64];
    __shared__ __align__(16) float Bs[16][64];
    const int tid = threadIdx.x;
    const int n0 = blockIdx.x * 64;
    const int m0 = blockIdx.y * 64;
    const int lm = tid >> 2;
    const int lk = (tid & 3) << 2;
    const int tn = tid & 15;
    const int tm = tid >> 4;

    float acc[4][4] = {};
    for (int k0 = 0; k0 < DD; k0 += 16) {
        float4 av = *(const float4*)(X  + (size_t)(m0 + lm) * DD + k0 + lk);
        float4 bv = *(const float4*)(Wx + (size_t)(n0 + lm) * DD + k0 + lk);
        __syncthreads();
        As[lk + 0][lm] = av.x; As[lk + 1][lm] = av.y;
        As[lk + 2][lm] = av.z; As[lk + 3][lm] = av.w;
        Bs[lk + 0][lm] = bv.x; Bs[lk + 1][lm] = bv.y;
        Bs[lk + 2][lm] = bv.z; Bs[lk + 3][lm] = bv.w;
        __syncthreads();
#pragma unroll
        for (int k = 0; k < 16; ++k) {
            float4 a4 = *(const float4*)&As[k][tm << 2];
            float4 b4 = *(const float4*)&Bs[k][tn << 2];
            float a[4] = {a4.x, a4.y, a4.z, a4.w};
            float b[4] = {b4.x, b4.y, b4.z, b4.w};
#pragma unroll
            for (int i = 0; i < 4; ++i)
#pragma unroll
                for (int j = 0; j < 4; ++j)
                    acc[i][j] += a[i] * b[j];
        }
    }
    float4 bv = *(const float4*)(bias + n0 + (tn << 2));
    float bias4[4] = {bv.x, bv.y, bv.z, bv.w};
#pragma unroll
    for (int i = 0; i < 4; ++i) {
        float4 o;
        o.x = acc[i][0] + bias4[0];
        o.y = acc[i][1] + bias4[1];
        o.z = acc[i][2] + bias4[2];
        o.w = acc[i][3] + bias4[3];
        *(float4*)(XP + (size_t)(m0 + (tm << 2) + i) * DD + n0 + (tn << 2)) = o;
    }
}

// ---------------------------------------------------------------------------
// Tagged h word: low 32 = float bits, high 32 = step tag.
// Agent (LLC) helpers for the fallback ring.
// ---------------------------------------------------------------------------
__device__ __forceinline__ void st_agent_u64(unsigned long long* p, unsigned long long v) {
    __hip_atomic_store(p, v, __ATOMIC_RELAXED, __HIP_MEMORY_SCOPE_AGENT);
}
__device__ __forceinline__ void st_plain_u64(unsigned long long* p, unsigned long long v) {
    __hip_atomic_store(p, v, __ATOMIC_RELAXED, __HIP_MEMORY_SCOPE_WORKGROUP);
}

// Stamp invalid tags into both rings (both slots).  Correctness does not
// depend on this (tag-mismatch just retries; t=1 bypasses the rings), it
// only guards against pathological workspace garbage.
__global__ void init_rings(unsigned long long* __restrict__ htL,
                           unsigned long long* __restrict__ htA)
{
    size_t i = (size_t)blockIdx.x * 256 + threadIdx.x;
    if (i < 2 * (size_t)BB * DD) {
        st_agent_u64(htL + i, 0xFFFFFFFF00000000ull);
        st_agent_u64(htA + i, 0xFFFFFFFF00000000ull);
    }
}

// ---------------------------------------------------------------------------
// Kernel 2: persistent gated-Elman scan.  R8: XCD-local synchronization.
//   Group = XCD-residency class: g = w&7 (empirical blockIdx%8 -> XCD),
//   idx = w>>3.  Group g's 32 WGs live on XCD g's 32 CUs (1 WG/CU) and sync
//   through their SHARED, COHERENT L2 (~0.1us RT) instead of the LLC
//   (~0.4-0.9us RT) -- R4/R6/R7 all plateaued at ~7.3us/step because every
//   serial protocol event crossed the LLC.
//   Protocol (no flags, no producer drain):
//     producer: plain-store tagged words to local ring (dirty in own L2)
//               + sc1-store to agent ring (fire-and-forget fallback).
//     consumer: sc0 bulk load (SE scope: L1-bypass, L2-served) + tag verify;
//               stale words retry at ~L2 latency; after 64 rounds a word
//               escalates to sc1 reads of the agent ring ->
//               CORRECTNESS NEVER DEPENDS ON THE WG->XCD MAPPING (G16);
//               broken mapping = slow (R7-like), never wrong/deadlocked.
//   Ring-of-2 overwrite safety (unchanged argument): a WG publishes t+1 only
//   after its whole WG verified ALL 5120 positions @t (20 words x 256 thr,
//   joined by the barrier), which implies every wave of every group WG
//   finished reading slot (t-1)&1.
//   t=1 reads h0 directly (no ring-init dependence).
//   Arithmetic identical to R7 (bitwise-same reduce tree / FMA order).
// ---------------------------------------------------------------------------
__launch_bounds__(256, 1) __global__
void gated_scan(const float* __restrict__ XP, const float* __restrict__ Z,
                const float* __restrict__ H0, const float* __restrict__ Wh,
                float* __restrict__ OUT,
                unsigned long long* __restrict__ htL,
                unsigned long long* __restrict__ htA)
{
    const int w   = blockIdx.x;
    const int g   = w & 7;        // batch group == XCD class
    const int idx = w >> 3;       // e-slice within group, 0..31
    const int b0  = g << 2;       // first of 4 batches
    const int e0  = idx * 40;     // first of 40 W_h rows
    const int tid = threadIdx.x;
    const int u   = tid >> 5;     // 0..7 -> e-row block
    const int p   = tid & 31;     // d-split lane

    // S: W staging chunks (25.6 KB) pre-loop, then double-buffered h
    // blocks S[2][4][1280] (2 x 20 KB) in the scan.
    __shared__ __align__(16) float S[2 * 4 * DD];    // 40 KB

    // ---- one-time: W fragment -> 200 persistent regs per thread ----------
    // thread (u,p) holds W[e0 + 5u + j][4p + 128k], j<5, k<10.
    // LDS round-trip prevents rematerialization (R5 lesson).
    const int d0 = p << 2;
    float4 wreg[5][10];
#pragma unroll 1
    for (int c = 0; c < 8; ++c) {
        __syncthreads();
        const float* src = Wh + (size_t)(e0 + 5 * c) * DD;   // 5 rows
        for (int i = tid; i < 5 * DD / 4; i += 256)
            ((float4*)S)[i] = ((const float4*)src)[i];
        __syncthreads();
        if (u == c) {
#pragma unroll
            for (int j = 0; j < 5; ++j)
#pragma unroll
                for (int k = 0; k < 10; ++k)
                    wreg[j][k] = *(const float4*)&S[j * DD + d0 + (k << 7)];
        }
    }
    __syncthreads();   // staging region overlaps h buffer 1; fence before use

    // Output lane mapping (reduce-scatter tree): valid low-3 patterns
    // {0,1,2,4,5} hold acc j = {0,1,2,3,4}; bits 3,4 give batch i.
    const int  lo3 = p & 7;
    const bool fin = (lo3 != 3) && (lo3 < 6);
    const int  jj  = (lo3 < 3) ? lo3 : (lo3 - 1);
    const int  ii  = ((p >> 3) & 1) + (((p >> 4) & 1) << 1);
    const int  bb  = b0 + ii;
    const int  ee  = e0 + u * 5 + jj;

    for (int t = 1; t <= TT; ++t) {
        // prefetch xp/z (independent of h -> overlaps the wait)
        const size_t oidx = ((size_t)(t - 1) * BB + bb) * DD + ee;
        float xpv = 0.f, zv = 0.f;
        if (fin) { xpv = XP[oidx]; zv = Z[oidx]; }

        float* Sh = S + (size_t)(t & 1) * (4 * DD);

        if (t == 1) {
            // h0 is a plain const input: read directly, no protocol.
            const float* h0b = H0 + (size_t)b0 * DD;
#pragma unroll
            for (int i = 0; i < 20; ++i)
                Sh[i * 256 + tid] = h0b[i * 256 + tid];
        } else {
            const unsigned tag = (unsigned)(t - 1);
            const int slot = (t - 1) & 1;
            const unsigned long long* hsL =
                htL + (size_t)slot * (BB * DD) + (size_t)b0 * DD;
            const unsigned long long* hsA =
                htA + (size_t)slot * (BB * DD) + (size_t)b0 * DD;

            unsigned long long v[20];
            // initial bulk: sc0 (SE scope) -> L1-bypass, served by local L2
#pragma unroll
            for (int i = 0; i < 20; ++i) {
                const unsigned long long* pl = hsL + i * 256 + tid;
                asm volatile("global_load_dwordx2 %0, %1, off sc0"
                             : "=v"(v[i]) : "v"(pl));
            }
            int rounds = 0;
            while (true) {
                asm volatile("s_waitcnt vmcnt(0)" ::: "memory");
                __builtin_amdgcn_sched_barrier(0);
                bool bad = false;
                const bool agent = (rounds >= 64);   // mapping-broken parachute
#pragma unroll
                for (int i = 0; i < 20; ++i) {
                    if ((unsigned)(v[i] >> 32) != tag) {
                        bad = true;
                        if (!agent) {
                            const unsigned long long* pl = hsL + i * 256 + tid;
                            asm volatile("global_load_dwordx2 %0, %1, off sc0"
                                         : "=v"(v[i]) : "v"(pl));
                        } else {
                            const unsigned long long* pa = hsA + i * 256 + tid;
                            asm volatile("global_load_dwordx2 %0, %1, off sc1"
                                         : "=v"(v[i]) : "v"(pa));
                        }
                    }
                }
                if (!bad) break;
                ++rounds;
            }
#pragma unroll
            for (int i = 0; i < 20; ++i)
                Sh[i * 256 + tid] = __uint_as_float((unsigned)v[i]);
        }
        __syncthreads();   // the only barrier per step: h block ready

        float acc[4][5] = {};
#pragma unroll
        for (int k = 0; k < 10; ++k) {
            const int d = d0 + (k << 7);
            float4 h4[4];
#pragma unroll
            for (int i = 0; i < 4; ++i)
                h4[i] = *(const float4*)&Sh[i * DD + d];
#pragma unroll
            for (int i = 0; i < 4; ++i)
#pragma unroll
                for (int j = 0; j < 5; ++j)
                    acc[i][j] += h4[i].x * wreg[j][k].x + h4[i].y * wreg[j][k].y
                               + h4[i].z * wreg[j][k].z + h4[i].w * wreg[j][k].w;
        }

        // ---- reduce-scatter over the 32 d-split lanes (bit5 untouched).
        // Same pairwise tree as R7 -> bitwise-identical.
        float s[20];
#pragma unroll
        for (int i = 0; i < 4; ++i)
#pragma unroll
            for (int j = 0; j < 5; ++j)
                s[i * 5 + j] = acc[i][j];
        // m=16: 20 -> 10
#pragma unroll
        for (int i = 0; i < 10; ++i) {
            float send = (p & 16) ? s[i] : s[10 + i];
            float recv = __shfl_xor(send, 16, 64);
            s[i] = ((p & 16) ? s[10 + i] : s[i]) + recv;
        }
        // m=8: 10 -> 5
#pragma unroll
        for (int i = 0; i < 5; ++i) {
            float send = (p & 8) ? s[i] : s[5 + i];
            float recv = __shfl_xor(send, 8, 64);
            s[i] = ((p & 8) ? s[5 + i] : s[i]) + recv;
        }
        // m=4: 5 -> 3 (pad)
        s[5] = 0.f;
#pragma unroll
        for (int i = 0; i < 3; ++i) {
            float send = (p & 4) ? s[i] : s[3 + i];
            float recv = __shfl_xor(send, 4, 64);
            s[i] = ((p & 4) ? s[3 + i] : s[i]) + recv;
        }
        // m=2: 3 -> 2 (pad)
        s[3] = 0.f;
#pragma unroll
        for (int i = 0; i < 2; ++i) {
            float send = (p & 2) ? s[i] : s[2 + i];
            float recv = __shfl_xor(send, 2, 64);
            s[i] = ((p & 2) ? s[2 + i] : s[i]) + recv;
        }
        // m=1: 2 -> 1
        {
            float send = (p & 1) ? s[0] : s[1];
            float recv = __shfl_xor(send, 1, 64);
            s[0] = ((p & 1) ? s[1] : s[0]) + recv;
        }

        if (fin) {
            const float hn = tanhf(xpv + s[0]);
            const float sg = zv / (1.0f + __expf(-zv));
            OUT[oidx] = hn * sg;
            const unsigned long long word =
                ((unsigned long long)(unsigned)t << 32) |
                (unsigned long long)__float_as_uint(hn);
            const size_t pos = (size_t)(t & 1) * (BB * DD) + (size_t)bb * DD + ee;
            st_plain_u64(htL + pos, word);   // local ring: dirty in own L2
            st_agent_u64(htA + pos, word);   // agent ring: LLC fallback
            if (t == TT)
                OUT[(size_t)TT * BB * DD + (size_t)bb * DD + ee] = hn;
        }
        // no drain, no flag: the tag inside each 8B word is the signal.
    }
}

// ---------------------------------------------------------------------------
extern "C" void kernel_launch(void* const* d_in, const int* in_sizes, int n_in,
                              void* d_out, int out_size, void* d_ws, size_t ws_size,
                              hipStream_t stream) {
    const float* x    = (const float*)d_in[0];  // [T,B,D]
    const float* z    = (const float*)d_in[1];  // [T,B,D]
    const float* h0   = (const float*)d_in[2];  // [B,D]
    const float* Wx   = (const float*)d_in[3];  // [D,D]
    const float* Wh   = (const float*)d_in[4];  // [D,D]
    const float* bias = (const float*)d_in[5];  // [D]
    float* out = (float*)d_out;

    // ws layout: xp 83.9 MB | local ring 655 KB | agent ring 655 KB
    float* xp = (float*)d_ws;
    unsigned long long* htL = (unsigned long long*)(xp + (size_t)TT * BB * DD);
    unsigned long long* htA = htL + 2 * (size_t)BB * DD;

    init_rings<<<(2 * BB * DD + 255) / 256, 256, 0, stream>>>(htL, htA);

    dim3 ggrid(DD / 64, (TT * BB) / 64);  // (20, 256)
    xproj_gemm<<<ggrid, 256, 0, stream>>>(x, Wx, bias, xp);
    gated_scan<<<256, 256, 0, stream>>>(xp, z, h0, Wh, out, htL, htA);
}

// Round 6
// 3435.241 us; speedup vs baseline: 8.3202x; 8.3202x over previous
//
#include <hip/hip_runtime.h>
#include <math.h>

#define TT 512
#define BB 32
#define DD 1280

// ---------------------------------------------------------------------------
// Kernel 1: x-projection GEMM.  XP[m][n] = bias[n] + sum_k X[m][k]*Wx[n][k]
// M = T*B = 16384, N = K = D = 1280.  fp32 (no fp32 MFMA on CDNA4).
// Unchanged (~550-700 us); revisit once the scan is < ~1.5x of it.
// ---------------------------------------------------------------------------
__launch_bounds__(256) __global__
void xproj_gemm(const float* __restrict__ X, const float* __restrict__ Wx,
                const float* __restrict__ bias, float* __restrict__ XP)
{
    __shared__ __align__(16) float As[16][64];
    __shared__ __align__(16) float Bs[16][64];
    const int tid = threadIdx.x;
    const int n0 = blockIdx.x * 64;
    const int m0 = blockIdx.y * 64;
    const int lm = tid >> 2;
    const int lk = (tid & 3) << 2;
    const int tn = tid & 15;
    const int tm = tid >> 4;

    float acc[4][4] = {};
    for (int k0 = 0; k0 < DD; k0 += 16) {
        float4 av = *(const float4*)(X  + (size_t)(m0 + lm) * DD + k0 + lk);
        float4 bv = *(const float4*)(Wx + (size_t)(n0 + lm) * DD + k0 + lk);
        __syncthreads();
        As[lk + 0][lm] = av.x; As[lk + 1][lm] = av.y;
        As[lk + 2][lm] = av.z; As[lk + 3][lm] = av.w;
        Bs[lk + 0][lm] = bv.x; Bs[lk + 1][lm] = bv.y;
        Bs[lk + 2][lm] = bv.z; Bs[lk + 3][lm] = bv.w;
        __syncthreads();
#pragma unroll
        for (int k = 0; k < 16; ++k) {
            float4 a4 = *(const float4*)&As[k][tm << 2];
            float4 b4 = *(const float4*)&Bs[k][tn << 2];
            float a[4] = {a4.x, a4.y, a4.z, a4.w};
            float b[4] = {b4.x, b4.y, b4.z, b4.w};
#pragma unroll
            for (int i = 0; i < 4; ++i)
#pragma unroll
                for (int j = 0; j < 4; ++j)
                    acc[i][j] += a[i] * b[j];
        }
    }
    float4 bv = *(const float4*)(bias + n0 + (tn << 2));
    float bias4[4] = {bv.x, bv.y, bv.z, bv.w};
#pragma unroll
    for (int i = 0; i < 4; ++i) {
        float4 o;
        o.x = acc[i][0] + bias4[0];
        o.y = acc[i][1] + bias4[1];
        o.z = acc[i][2] + bias4[2];
        o.w = acc[i][3] + bias4[3];
        *(float4*)(XP + (size_t)(m0 + (tm << 2) + i) * DD + n0 + (tn << 2)) = o;
    }
}

// ---------------------------------------------------------------------------
// Tagged h word: low 32 = float bits, high 32 = step tag.  Agent scope
// (__hip_atomic_*, LLC-coherent) is the only HW-validated visibility path
// (R8 lesson: sc0/local-L2 protocols never became visible -> livelock;
// R9 lesson: avoid raw inline-asm for the protocol path entirely).
// ---------------------------------------------------------------------------
__device__ __forceinline__ unsigned long long ld_agent_u64(const unsigned long long* p) {
    return __hip_atomic_load(p, __ATOMIC_RELAXED, __HIP_MEMORY_SCOPE_AGENT);
}
__device__ __forceinline__ void st_agent_u64(unsigned long long* p, unsigned long long v) {
    __hip_atomic_store(p, v, __ATOMIC_RELAXED, __HIP_MEMORY_SCOPE_AGENT);
}

// Stamp invalid tags into both slots (guards against workspace garbage that
// could alias a valid tag; t=1 bypasses the ring entirely via h0).
__global__ void init_ring(unsigned long long* __restrict__ ht)
{
    size_t i = (size_t)blockIdx.x * 256 + threadIdx.x;
    if (i < 2 * (size_t)BB * DD)
        st_agent_u64(ht + i, 0xFFFFFFFF00000000ull);
}

// ---------------------------------------------------------------------------
// Kernel 2: persistent gated-Elman scan.  R10: speculative pipelined
// protocol on the pure __hip_atomic path (no inline asm anywhere).
//   8 batch-groups x 4 batches; 32 WGs/group, each owns 40 W_h rows.
//   Per-step timeline:
//     stage verified v[] (h_{t-1}) -> LDS     (t=1: from h0 directly)
//     __syncthreads()                          (the only barrier)
//     ISSUE 20 agent loads for h_t into v[]    (fly during compute; first
//                                               use is in the verify below,
//                                               so waitcnt lands there)
//     k-loop; reduce-scatter; publish own h_t (tagged 8B agent store)
//     VERIFY v[] tags == t; re-load stale words until fresh (R6-style)
//   Rationale: R4/R6/R7 plateaued ~7.3us/step; the detect+load LLC round
//   trips sat strictly AFTER compute.  Issuing the loads one compute-phase
//   early overlaps ~1 RT + detection with compute.
//   Ring-of-2 overwrite safety (unchanged): a WG publishes t+1 only after
//   its whole WG verified ALL 5120 positions @t (20 words x 256 thr,
//   barrier-joined), so every reader of slot (t-1)&1 is done before any
//   writer of tag t+1 touches it.  8B tagged words are single-instruction
//   loads/stores -> no torn reads.  Speculative reads of a slot being
//   written just see old-tag words and retry.
//   Arithmetic bitwise-identical to R6/R7 (same tree, same FMA order).
// ---------------------------------------------------------------------------
__launch_bounds__(256, 1) __global__
void gated_scan(const float* __restrict__ XP, const float* __restrict__ Z,
                const float* __restrict__ H0, const float* __restrict__ Wh,
                float* __restrict__ OUT,
                unsigned long long* __restrict__ ht)
{
    const int w   = blockIdx.x;
    const int g   = w & 7;        // batch group (label only, no XCD assumption)
    const int idx = w >> 3;       // e-slice within group, 0..31
    const int b0  = g << 2;       // first of 4 batches
    const int e0  = idx * 40;     // first of 40 W_h rows
    const int tid = threadIdx.x;
    const int u   = tid >> 5;     // 0..7 -> e-row block
    const int p   = tid & 31;     // d-split lane

    // S: W staging chunks (25.6 KB) pre-loop, then double-buffered h
    // blocks S[2][4][1280] (2 x 20 KB) in the scan.
    __shared__ __align__(16) float S[2 * 4 * DD];    // 40 KB

    // ---- one-time: W fragment -> 200 persistent regs per thread ----------
    // thread (u,p) holds W[e0 + 5u + j][4p + 128k], j<5, k<10.
    // LDS round-trip prevents rematerialization (R5 lesson).
    const int d0 = p << 2;
    float4 wreg[5][10];
#pragma unroll 1
    for (int c = 0; c < 8; ++c) {
        __syncthreads();
        const float* src = Wh + (size_t)(e0 + 5 * c) * DD;   // 5 rows
        for (int i = tid; i < 5 * DD / 4; i += 256)
            ((float4*)S)[i] = ((const float4*)src)[i];
        __syncthreads();
        if (u == c) {
#pragma unroll
            for (int j = 0; j < 5; ++j)
#pragma unroll
                for (int k = 0; k < 10; ++k)
                    wreg[j][k] = *(const float4*)&S[j * DD + d0 + (k << 7)];
        }
    }
    __syncthreads();   // staging region overlaps h buffer 1; fence before use

    // Output lane mapping (reduce-scatter tree): valid low-3 patterns
    // {0,1,2,4,5} hold acc j = {0,1,2,3,4}; bits 3,4 give batch i.
    const int  lo3 = p & 7;
    const bool fin = (lo3 != 3) && (lo3 < 6);
    const int  jj  = (lo3 < 3) ? lo3 : (lo3 - 1);
    const int  ii  = ((p >> 3) & 1) + (((p >> 4) & 1) << 1);
    const int  bb  = b0 + ii;
    const int  ee  = e0 + u * 5 + jj;

    unsigned long long v[20];   // tagged words: h_{t-1} at loop top,
                                // then in-flight h_t after the barrier

    for (int t = 1; t <= TT; ++t) {
        // prefetch xp/z (independent of h; consumed after the compute)
        const size_t oidx = ((size_t)(t - 1) * BB + bb) * DD + ee;
        float xpv = 0.f, zv = 0.f;
        if (fin) { xpv = XP[oidx]; zv = Z[oidx]; }

        // ---- stage h_{t-1} into LDS (verified last iteration; t=1: h0) ---
        float* Sh = S + (size_t)(t & 1) * (4 * DD);
        if (t == 1) {
            const float* h0b = H0 + (size_t)b0 * DD;
#pragma unroll
            for (int i = 0; i < 20; ++i)
                Sh[i * 256 + tid] = h0b[i * 256 + tid];
        } else {
#pragma unroll
            for (int i = 0; i < 20; ++i)
                Sh[i * 256 + tid] = __uint_as_float((unsigned)v[i]);
        }
        __syncthreads();   // the only barrier per step: h block ready

        // ---- speculative issue of step-t words into the ring slot t&1
        // (tags will read == t once peers publish).  Issued here -- after
        // the barrier, so the barrier's vmcnt drain doesn't stall on them --
        // and first USED in the verify loop below, so they stay in flight
        // across the whole compute phase.
        const unsigned long long* hn_ =
            ht + (size_t)(t & 1) * (BB * DD) + (size_t)b0 * DD;
        if (t < TT) {
#pragma unroll
            for (int i = 0; i < 20; ++i)
                v[i] = ld_agent_u64(hn_ + i * 256 + tid);
        }

        float acc[4][5] = {};
#pragma unroll
        for (int k = 0; k < 10; ++k) {
            const int d = d0 + (k << 7);
            float4 h4[4];
#pragma unroll
            for (int i = 0; i < 4; ++i)
                h4[i] = *(const float4*)&Sh[i * DD + d];
#pragma unroll
            for (int i = 0; i < 4; ++i)
#pragma unroll
                for (int j = 0; j < 5; ++j)
                    acc[i][j] += h4[i].x * wreg[j][k].x + h4[i].y * wreg[j][k].y
                               + h4[i].z * wreg[j][k].z + h4[i].w * wreg[j][k].w;
        }

        // ---- reduce-scatter over the 32 d-split lanes (bit5 untouched).
        // Same pairwise tree as R7 -> bitwise-identical.
        float s[20];
#pragma unroll
        for (int i = 0; i < 4; ++i)
#pragma unroll
            for (int j = 0; j < 5; ++j)
                s[i * 5 + j] = acc[i][j];
        // m=16: 20 -> 10
#pragma unroll
        for (int i = 0; i < 10; ++i) {
            float send = (p & 16) ? s[i] : s[10 + i];
            float recv = __shfl_xor(send, 16, 64);
            s[i] = ((p & 16) ? s[10 + i] : s[i]) + recv;
        }
        // m=8: 10 -> 5
#pragma unroll
        for (int i = 0; i < 5; ++i) {
            float send = (p & 8) ? s[i] : s[5 + i];
            float recv = __shfl_xor(send, 8, 64);
            s[i] = ((p & 8) ? s[5 + i] : s[i]) + recv;
        }
        // m=4: 5 -> 3 (pad)
        s[5] = 0.f;
#pragma unroll
        for (int i = 0; i < 3; ++i) {
            float send = (p & 4) ? s[i] : s[3 + i];
            float recv = __shfl_xor(send, 4, 64);
            s[i] = ((p & 4) ? s[3 + i] : s[i]) + recv;
        }
        // m=2: 3 -> 2 (pad)
        s[3] = 0.f;
#pragma unroll
        for (int i = 0; i < 2; ++i) {
            float send = (p & 2) ? s[i] : s[2 + i];
            float recv = __shfl_xor(send, 2, 64);
            s[i] = ((p & 2) ? s[2 + i] : s[i]) + recv;
        }
        // m=1: 2 -> 1
        {
            float send = (p & 1) ? s[0] : s[1];
            float recv = __shfl_xor(send, 1, 64);
            s[0] = ((p & 1) ? s[1] : s[0]) + recv;
        }

        if (fin) {
            const float hn = tanhf(xpv + s[0]);
            // publish FIRST (critical path for peers), then the output math
            st_agent_u64(ht + (size_t)(t & 1) * (BB * DD) + (size_t)bb * DD + ee,
                         ((unsigned long long)(unsigned)t << 32) |
                         (unsigned long long)__float_as_uint(hn));
            const float sg = zv / (1.0f + __expf(-zv));
            OUT[oidx] = hn * sg;
            if (t == TT)
                OUT[(size_t)TT * BB * DD + (size_t)bb * DD + ee] = hn;
        }

        // ---- verify the in-flight step-t words; re-load stale ones -------
        // (R6-validated retry shape: batched rounds of conditional reloads.)
        if (t < TT) {
            const unsigned need = (unsigned)t;
            bool bad;
            do {
                bad = false;
#pragma unroll
                for (int i = 0; i < 20; ++i)
                    if ((unsigned)(v[i] >> 32) != need) {
                        v[i] = ld_agent_u64(hn_ + i * 256 + tid);
                        bad = true;
                    }
            } while (bad);
        }
    }
}

// ---------------------------------------------------------------------------
extern "C" void kernel_launch(void* const* d_in, const int* in_sizes, int n_in,
                              void* d_out, int out_size, void* d_ws, size_t ws_size,
                              hipStream_t stream) {
    const float* x    = (const float*)d_in[0];  // [T,B,D]
    const float* z    = (const float*)d_in[1];  // [T,B,D]
    const float* h0   = (const float*)d_in[2];  // [B,D]
    const float* Wx   = (const float*)d_in[3];  // [D,D]
    const float* Wh   = (const float*)d_in[4];  // [D,D]
    const float* bias = (const float*)d_in[5];  // [D]
    float* out = (float*)d_out;

    // ws layout: xp 83.9 MB | tagged 2-slot h ring 655 KB
    float* xp = (float*)d_ws;
    unsigned long long* ht = (unsigned long long*)(xp + (size_t)TT * BB * DD);

    init_ring<<<(2 * BB * DD + 255) / 256, 256, 0, stream>>>(ht);

    dim3 ggrid(DD / 64, (TT * BB) / 64);  // (20, 256)
    xproj_gemm<<<ggrid, 256, 0, stream>>>(x, Wx, bias, xp);
    gated_scan<<<256, 256, 0, stream>>>(xp, z, h0, Wh, out, ht);
}